// Round 8
// baseline (478.942 us; speedup 1.0000x reference)
//
#include <hip/hip_runtime.h>
#include <math.h>

#define NB 65536
#define DIM 256

// Fused-kernel W image: fp16, col-major per expert: [L][e][n][k], 512 B per
// column (k contiguous). No padding needed — B is read straight to registers.
#define LAYB 524288   // 4 experts * 256 cols * 512 B

typedef _Float16 half8 __attribute__((ext_vector_type(8)));   // 4 VGPRs
typedef float    f32x4 __attribute__((ext_vector_type(4)));

// ---- W pre-pass: fp32 [e][k][n] -> fp16 [L][e][n][k] ----
// One thread per 16B output chunk (3 L * 4 e * 32 k8 * 256 n = 98304).
__global__ __launch_bounds__(256) void convert_w(
    const float* __restrict__ W1, const float* __restrict__ W2,
    const float* __restrict__ W3, char* __restrict__ W16T)
{
  const int g  = blockIdx.x * 256 + threadIdx.x;
  const int n  = g & 255;          // output column
  const int k8 = (g >> 8) & 31;    // 16B k-chunk (8 halves)
  const int e  = (g >> 13) & 3;
  const int L  = g >> 15;
  const float* WL  = (L == 0) ? W1 : (L == 1) ? W2 : W3;
  const float* src = WL + (size_t)e * DIM * DIM + (size_t)k8 * 8 * DIM + n;
  half8 h;
  #pragma unroll
  for (int j = 0; j < 8; ++j) h[j] = (_Float16)src[(size_t)j * DIM];
  *(half8*)(W16T + (size_t)L * LAYB + ((size_t)e << 17)
            + (size_t)n * 512 + k8 * 16) = h;
}

// ---- Fused 3-layer cyclic-MoE ----
// R8 design (post 7 rounds of barrier-synced LDS-staging all pinned at
// 60-75us/layer with every pipe <25% busy):
//   - ONE kernel, 3 layers. H1/H2 never touch HBM: they live in LDS
//     (sH[128][264], proven 528B bank-spread stride).
//   - NO LDS W staging, NO per-phase barriers: B fragments load from the
//     L2-resident fp16 W image straight into registers, double-buffered
//     (bA/bB, static alternation). A 32-MFMA cluster is ~620 cyc of issue
//     on its SIMD (19.4 cyc/MFMA per SIMD) — covers L2 latency via ILP.
//   - 5 __syncthreads total (prologue + 2 per layer boundary).
//   - block = 512 thr = 8 waves = (rg 0..1 x 64 rows) x (cg 0..3 x 64 cols);
//     wave = 64 rows x 64 cols, m_rep=4, nt 0..3 (16 cols each).
//   - coefficients in LDS sC2[e][row] (f32x4 read per m: 4 r-coeffs);
//     bias folded into combine: fin += cc * (acc + be) (exact algebra).
//   - scales: L2 out pre-scaled 1/8 (fp16 range), L3 bias x1/8 + out x8.
template<bool WF16>
__global__ __launch_bounds__(512, 1) void moe_fused(
    const float* __restrict__ X,
    const float* __restrict__ phi,
    const float* __restrict__ W1f, const float* __restrict__ W2f,
    const float* __restrict__ W3f,
    const char* __restrict__ W16,     // staged fp16 image (3*LAYB) or null
    const float* __restrict__ b1, const float* __restrict__ b2,
    const float* __restrict__ b3,
    float* __restrict__ Out)
{
  __shared__ _Float16 sH[128][264];      // 67584 B inter-layer activations
  __shared__ float sC2[4][128];          // coeffs, expert-major
  __shared__ float sBias[3][4][DIM];     // all 3 layers' biases

  const int tid  = threadIdx.x;
  const int row0 = blockIdx.x * 128;
  const int wave = tid >> 6;
  const int lane = tid & 63;
  const int quad = lane >> 4;
  const int l15  = lane & 15;
  const int rg   = wave >> 2;            // row group (64 rows)
  const int cg   = wave & 3;             // col group (64 cols)

  // --- coefficients (reference _phase_mix), expert-major layout ---
  if (tid < 128) {
    const float w  = phi[row0 + tid] * (float)(2.0 / M_PI);  // [0,4]
    const int   wi = (int)w;
    const float w2 = w * w, w3 = w2 * w;
    const float cf[4] = {
      -0.5f * w + w2 - 0.5f * w3,
      -2.5f * w2 + 1.5f * w3,
       0.5f * w + 2.0f * w2 - 1.5f * w3,
      -0.5f * w2 + 0.5f * w3 };
    #pragma unroll
    for (int e = 0; e < 4; ++e) sC2[e][tid] = cf[(e + 1 - wi) & 3];
  }
  // --- biases: 3*4*256 floats ---
  for (int i = tid; i < 3 * 4 * DIM; i += 512) {
    const int L = i >> 10, rem = i & 1023;
    const float* bL = (L == 0) ? b1 : (L == 1) ? b2 : b3;
    sBias[L][rem >> 8][rem & 255] = bL[rem];
  }

  // --- A fragments: wave owns 64 rows = 4 m-tiles x 8 k-chunks (128 VGPR) ---
  half8 afr[4][8];
  #pragma unroll
  for (int m = 0; m < 4; ++m) {
    const float* xr = X + (size_t)(row0 + rg * 64 + m * 16 + l15) * DIM;
    #pragma unroll
    for (int kb = 0; kb < 8; ++kb) {
      const float4 a = *(const float4*)(xr + kb * 32 + quad * 8);
      const float4 b = *(const float4*)(xr + kb * 32 + quad * 8 + 4);
      half8 h;
      h[0] = (_Float16)a.x; h[1] = (_Float16)a.y;
      h[2] = (_Float16)a.z; h[3] = (_Float16)a.w;
      h[4] = (_Float16)b.x; h[5] = (_Float16)b.y;
      h[6] = (_Float16)b.z; h[7] = (_Float16)b.w;
      afr[m][kb] = h;
    }
  }

  half8 bA[8], bB[8];

  // B-fragment loader: 8 x 16B global loads (L2-resident W) into registers.
  auto loadB = [&](half8 (&b)[8], int L, int e, int nt) {
    if constexpr (WF16) {
      const char* p = W16 + (size_t)L * LAYB + ((size_t)e << 17)
                    + (size_t)(cg * 64 + nt * 16 + l15) * 512 + quad * 16;
      #pragma unroll
      for (int kb = 0; kb < 8; ++kb)
        b[kb] = *(const half8*)(p + kb * 64);
    } else {
      // fp32 fallback (no workspace): scalar strided reads + cvt.
      const float* Wf = (L == 0) ? W1f : (L == 1) ? W2f : W3f;
      const int n = cg * 64 + nt * 16 + l15;
      #pragma unroll
      for (int kb = 0; kb < 8; ++kb) {
        half8 h;
        #pragma unroll
        for (int j = 0; j < 8; ++j)
          h[j] = (_Float16)Wf[(size_t)e * DIM * DIM
                              + (size_t)(kb * 32 + quad * 8 + j) * DIM + n];
        b[kb] = h;
      }
    }
  };

  // 32-MFMA cluster + combine (bias folded: fin += cc * (acc + be*bs)).
  auto compute = [&](const half8 (&b)[8], int L, int e, int nt,
                     f32x4 (&fin)[4], float bs) {
    f32x4 acc[4];
    #pragma unroll
    for (int m = 0; m < 4; ++m) acc[m] = (f32x4){0.f, 0.f, 0.f, 0.f};
    #pragma unroll
    for (int kb = 0; kb < 8; ++kb) {
      acc[0] = __builtin_amdgcn_mfma_f32_16x16x32_f16(afr[0][kb], b[kb], acc[0], 0, 0, 0);
      acc[1] = __builtin_amdgcn_mfma_f32_16x16x32_f16(afr[1][kb], b[kb], acc[1], 0, 0, 0);
      acc[2] = __builtin_amdgcn_mfma_f32_16x16x32_f16(afr[2][kb], b[kb], acc[2], 0, 0, 0);
      acc[3] = __builtin_amdgcn_mfma_f32_16x16x32_f16(afr[3][kb], b[kb], acc[3], 0, 0, 0);
    }
    const float be = sBias[L][e][cg * 64 + nt * 16 + l15] * bs;
    const f32x4 be4 = {be, be, be, be};
    #pragma unroll
    for (int m = 0; m < 4; ++m) {
      const f32x4 cc = *(const f32x4*)&sC2[e][rg * 64 + m * 16 + quad * 4];
      fin[m] += cc * (acc[m] + be4);
    }
  };

  // One layer: 4 nt x 4 e, B double-buffered with static bA/bB alternation.
  auto run_layer = [&](int L, float bs, float os, bool relu, bool toGlobal) {
    loadB(bA, L, 0, 0);
    for (int nt = 0; nt < 4; ++nt) {
      f32x4 fin[4];
      #pragma unroll
      for (int m = 0; m < 4; ++m) fin[m] = (f32x4){0.f, 0.f, 0.f, 0.f};

      loadB(bB, L, 1, nt);                 compute(bA, L, 0, nt, fin, bs);
      loadB(bA, L, 2, nt);                 compute(bB, L, 1, nt, fin, bs);
      loadB(bB, L, 3, nt);                 compute(bA, L, 2, nt, fin, bs);
      if (nt < 3) loadB(bA, L, 0, nt + 1); compute(bB, L, 3, nt, fin, bs);

      const int n_l = cg * 64 + nt * 16 + l15;   // col = lane&15 (proven C/D map)
      #pragma unroll
      for (int m = 0; m < 4; ++m)
        #pragma unroll
        for (int r = 0; r < 4; ++r) {
          const int row_l = rg * 64 + m * 16 + quad * 4 + r;  // row = quad*4+reg
          float v = fin[m][r];
          if (relu) v = fmaxf(v, 0.f);
          v *= os;
          if (toGlobal) Out[(size_t)(row0 + row_l) * DIM + n_l] = v;
          else          sH[row_l][n_l] = (_Float16)v;
        }
    }
  };

  // A-fragment reload from LDS H (row stride 264 halves; same frag layout).
  auto reload_afr = [&]() {
    #pragma unroll
    for (int m = 0; m < 4; ++m) {
      const int row = rg * 64 + m * 16 + l15;
      #pragma unroll
      for (int kb = 0; kb < 8; ++kb)
        afr[m][kb] = *(const half8*)&sH[row][kb * 32 + quad * 8];
    }
  };

  __syncthreads();                       // sC2 + sBias ready

  run_layer(0, 1.0f,   1.0f,  true,  false);   // X -> H1 (fp16, LDS)
  __syncthreads();                       // all H1 writes done
  reload_afr();
  __syncthreads();                       // all H1 reads done (H2 may overwrite)

  run_layer(1, 1.0f,   0.125f, true,  false);  // H1 -> H2 (x1/8, LDS)
  __syncthreads();
  reload_afr();
  __syncthreads();

  run_layer(2, 0.125f, 8.0f,   false, true);   // H2 -> Out (undo 1/8)
}

extern "C" void kernel_launch(void* const* d_in, const int* in_sizes, int n_in,
                              void* d_out, int out_size, void* d_ws, size_t ws_size,
                              hipStream_t stream) {
  const float* X   = (const float*)d_in[0];
  const float* phi = (const float*)d_in[1];
  const float* W1  = (const float*)d_in[2];
  const float* b1  = (const float*)d_in[3];
  const float* W2  = (const float*)d_in[4];
  const float* b2  = (const float*)d_in[5];
  const float* W3  = (const float*)d_in[6];
  const float* b3  = (const float*)d_in[7];

  float* out = (float*)d_out;
  const size_t w16_bytes = (size_t)3 * LAYB;   // 1.5 MB — only ws use now

  dim3 grid(NB / 128);    // 512 blocks
  dim3 block(512);

  if (ws_size >= w16_bytes) {
    char* W16 = (char*)d_ws;
    convert_w<<<dim3(384), dim3(256), 0, stream>>>(W1, W2, W3, W16);
    moe_fused<true><<<grid, block, 0, stream>>>(
        X, phi, W1, W2, W3, W16, b1, b2, b3, out);
  } else {
    moe_fused<false><<<grid, block, 0, stream>>>(
        X, phi, W1, W2, W3, nullptr, b1, b2, b3, out);
  }
}